// Round 13
// baseline (353.238 us; speedup 1.0000x reference)
//
#include <hip/hip_runtime.h>
#include <hip/hip_bf16.h>
#include <hip/hip_fp8.h>
#include <math.h>

typedef __attribute__((ext_vector_type(8))) short bf16x8;
typedef __attribute__((ext_vector_type(4))) float f32x4;
typedef __attribute__((ext_vector_type(4))) unsigned int u32x4;
typedef __attribute__((ext_vector_type(4))) int i32x4;
typedef unsigned short ushort_t;
typedef unsigned char uchar_t;

#define BUCKET_SHIFT 6
#define BUCKET_CAP   64
#define SB_ 32          // radix blocks per direction

__device__ inline short f2b(float f) {
    __hip_bfloat16 h = __float2bfloat16(f);
    return __builtin_bit_cast(short, h);
}
__device__ inline float b2f(unsigned short u) {
    return __builtin_bit_cast(float, (unsigned int)u << 16);
}
__device__ inline float blo(unsigned int w) {
    return __builtin_bit_cast(float, w << 16);
}
__device__ inline float bhi(unsigned int w) {
    return __builtin_bit_cast(float, w & 0xffff0000u);
}
__device__ inline uchar_t f2f8(float f) {
    __hip_fp8_e4m3 h(f);
    return (uchar_t)h.__x;
}
__device__ inline float f82f(unsigned int u) {
    __hip_fp8_e4m3 h;
    h.__x = (__hip_fp8_storage_t)(u & 0xff);
    return (float)h;
}

// ---------------- prep: fold rel-projections into weights, cast to bf16 ----------------
__global__ __launch_bounds__(256) void prep_kernel(
    const float* __restrict__ w_in,
    const float* __restrict__ kw, const float* __restrict__ kb,
    const float* __restrict__ qw, const float* __restrict__ qb,
    const float* __restrict__ vw, const float* __restrict__ vb,
    const float* __restrict__ aw,
    const float* __restrict__ a_rel, const float* __restrict__ m_rel,
    const float* __restrict__ p_rel,
    short* __restrict__ wstem, short* __restrict__ Wcat,
    float* __restrict__ Bcat, short* __restrict__ Awb)
{
    int bid = blockIdx.x, tid = threadIdx.x;
    if (bid >= 4) {
        int t = bid - 4;
        for (int i = tid; i < 16384; i += 256)
            wstem[t * 16384 + i] = f2b(w_in[t * 16384 + i]);
        return;
    }
    int base = bid;
    const float* KW = kw + base * 4096;
    const float* QW = qw + base * 4096;
    const float* VW = vw + base * 4096;
    const float* AR = a_rel + base * 512;
    const float* MR = m_rel + base * 512;
    const float* PR = p_rel + base * 8;
    short* WC = Wcat + base * 12288;
    float* BC = Bcat + base * 192;

    for (int i = tid; i < 4096; i += 256) WC[i] = f2b(QW[i]);
    for (int i = tid; i < 4096; i += 256) {
        int out = i >> 6, in = i & 63;
        int h = out >> 3, e = out & 7;
        float s = PR[h] * 0.35355339059327373f;
        float acc = 0.f;
        #pragma unroll
        for (int d = 0; d < 8; ++d) acc += KW[(h * 8 + d) * 64 + in] * AR[h * 64 + d * 8 + e];
        WC[4096 + i] = f2b(acc * s);
    }
    for (int i = tid; i < 4096; i += 256) {
        int out = i >> 6, in = i & 63;
        int h = out >> 3, e = out & 7;
        float acc = 0.f;
        #pragma unroll
        for (int d = 0; d < 8; ++d) acc += VW[(h * 8 + d) * 64 + in] * MR[h * 64 + d * 8 + e];
        WC[8192 + i] = f2b(acc);
    }
    if (tid < 64) {
        BC[tid] = qb[base * 64 + tid];
    } else if (tid < 128) {
        int out = tid - 64;
        int h = out >> 3, e = out & 7;
        float s = PR[h] * 0.35355339059327373f;
        float acc = 0.f;
        #pragma unroll
        for (int d = 0; d < 8; ++d) acc += kb[base * 64 + h * 8 + d] * AR[h * 64 + d * 8 + e];
        BC[64 + out] = acc * s;
    } else if (tid < 192) {
        int out = tid - 128;
        int h = out >> 3, e = out & 7;
        float acc = 0.f;
        #pragma unroll
        for (int d = 0; d < 8; ++d) acc += vb[base * 64 + h * 8 + d] * MR[h * 64 + d * 8 + e];
        BC[128 + out] = acc;
    }
    for (int i = tid; i < 4096; i += 256) Awb[base * 4096 + i] = f2b(aw[base * 4096 + i]);
}

// ---------------- merged stem ----------------
__global__ __launch_bounds__(256) void stem2_mfma(
    const float* __restrict__ X1, const float* __restrict__ X2,
    const short* __restrict__ Wb, const float* __restrict__ B1, const float* __restrict__ B2,
    short* __restrict__ H1, short* __restrict__ H2, int N1, int N2, int nt1)
{
    const float* X; const short* Wsrc; const float* B; short* Hb; int N; int tb;
    if (blockIdx.x < nt1) { X = X1; Wsrc = Wb;         B = B1; Hb = H1; N = N1; tb = blockIdx.x; }
    else                  { X = X2; Wsrc = Wb + 16384; B = B2; Hb = H2; N = N2; tb = blockIdx.x - nt1; }
    __shared__ short Ws[64 * 256];
    int tid = threadIdx.x;
    #pragma unroll
    for (int k = 0; k < 8; ++k) {
        int u = tid + k * 256;
        int row = u >> 5, c = u & 31;
        u32x4 v = *reinterpret_cast<const u32x4*>(Wsrc + row * 256 + c * 8);
        *reinterpret_cast<u32x4*>(&Ws[row * 256 + ((c ^ (row & 7)) << 3)]) = v;
    }
    __syncthreads();
    int w = tid >> 6, l = tid & 63;
    int g = l >> 4, q = l & 15;
    int row = tb * 64 + w * 16 + q;
    bool rok = row < N;
    f32x4 acc[4] = {};
    const float* xr = X + (size_t)row * 256 + g * 8;
    #pragma unroll
    for (int s = 0; s < 8; ++s) {
        bf16x8 a = {};
        if (rok) {
            float4 x0 = *reinterpret_cast<const float4*>(xr + s * 32);
            float4 x1 = *reinterpret_cast<const float4*>(xr + s * 32 + 4);
            a[0] = f2b(x0.x); a[1] = f2b(x0.y); a[2] = f2b(x0.z); a[3] = f2b(x0.w);
            a[4] = f2b(x1.x); a[5] = f2b(x1.y); a[6] = f2b(x1.z); a[7] = f2b(x1.w);
        }
        #pragma unroll
        for (int n = 0; n < 4; ++n) {
            int br = n * 16 + q;
            int c = s * 4 + g;
            bf16x8 b = *reinterpret_cast<bf16x8*>(&Ws[br * 256 + ((c ^ (br & 7)) << 3)]);
            acc[n] = __builtin_amdgcn_mfma_f32_16x16x32_bf16(a, b, acc[n], 0, 0, 0);
        }
    }
    int orow0 = tb * 64 + w * 16 + g * 4;
    #pragma unroll
    for (int n = 0; n < 4; ++n) {
        int col = n * 16 + q;
        float bias = B[col];
        #pragma unroll
        for (int r = 0; r < 4; ++r) {
            int orow = orow0 + r;
            if (orow < N)
                Hb[(size_t)orow * 64 + col] = f2b(fmaxf(acc[n][r] + bias, 0.f));
        }
    }
}

// ---------------- kqv: q bf16, KV fp8 interleaved ----------------
__global__ __launch_bounds__(256) void kqv2_mfma(
    const short* __restrict__ H1, const short* __restrict__ Wc1, const float* __restrict__ Bc1,
    short* __restrict__ Q1, uchar_t* __restrict__ KV1, int N1,
    const short* __restrict__ H2, const short* __restrict__ Wc2, const float* __restrict__ Bc2,
    short* __restrict__ Q2, uchar_t* __restrict__ KV2, int N2, int nt1)
{
    const short* Hb; const short* Wcat; const float* Bcat; short* Qb; uchar_t* KV; int N; int tb;
    if (blockIdx.x < nt1) { Hb = H1; Wcat = Wc1; Bcat = Bc1; Qb = Q1; KV = KV1; N = N1; tb = blockIdx.x; }
    else                  { Hb = H2; Wcat = Wc2; Bcat = Bc2; Qb = Q2; KV = KV2; N = N2; tb = blockIdx.x - nt1; }
    __shared__ short Ws[192 * 64];
    int tid = threadIdx.x;
    #pragma unroll
    for (int k = 0; k < 6; ++k) {
        int u = tid + k * 256;
        int row = u >> 3, c = u & 7;
        u32x4 v = *reinterpret_cast<const u32x4*>(Wcat + row * 64 + c * 8);
        *reinterpret_cast<u32x4*>(&Ws[row * 64 + ((c ^ (row & 7)) << 3)]) = v;
    }
    __syncthreads();
    int w = tid >> 6, l = tid & 63;
    int g = l >> 4, q = l & 15;
    int arow = tb * 64 + w * 16 + q;
    bool rok = arow < N;
    bf16x8 a0 = {}, a1 = {};
    if (rok) {
        a0 = *reinterpret_cast<const bf16x8*>(Hb + (size_t)arow * 64 + g * 8);
        a1 = *reinterpret_cast<const bf16x8*>(Hb + (size_t)arow * 64 + 32 + g * 8);
    }
    f32x4 acc[12] = {};
    #pragma unroll
    for (int n = 0; n < 12; ++n) {
        int br = n * 16 + q;
        bf16x8 b0 = *reinterpret_cast<bf16x8*>(&Ws[br * 64 + ((0 * 4 + g) ^ (br & 7)) * 8]);
        acc[n] = __builtin_amdgcn_mfma_f32_16x16x32_bf16(a0, b0, acc[n], 0, 0, 0);
        bf16x8 b1 = *reinterpret_cast<bf16x8*>(&Ws[br * 64 + ((1 * 4 + g) ^ (br & 7)) * 8]);
        acc[n] = __builtin_amdgcn_mfma_f32_16x16x32_bf16(a1, b1, acc[n], 0, 0, 0);
    }
    int orow0 = tb * 64 + w * 16 + g * 4;
    #pragma unroll
    for (int n = 0; n < 12; ++n) {
        int col = n * 16 + q;
        float bias = Bcat[col];
        #pragma unroll
        for (int r = 0; r < 4; ++r) {
            int orow = orow0 + r;
            if (orow < N) {
                float v = acc[n][r] + bias;
                if (n < 4)      Qb[(size_t)orow * 64 + col]              = f2b(v);
                else if (n < 8) KV[(size_t)orow * 128 + 2 * (col - 64)]  = f2f8(v);
                else            KV[(size_t)orow * 128 + 2 * (col - 128) + 1] = f2f8(v);
            }
        }
    }
}

// ---------------- radix pass 1: per-(block,bin) histogram, bin = dst>>6 ----------------
__global__ __launch_bounds__(256) void radix_hist(
    const int* __restrict__ e12, const int* __restrict__ e21,
    int* __restrict__ histA, int* __restrict__ histB,
    int E, int nbA, int nbB)
{
    int blk = blockIdx.x;
    bool dirA = blk < SB_;
    int b = dirA ? blk : blk - SB_;
    const int* dstp = dirA ? (e12 + E) : (e21 + E);
    int nb = dirA ? nbA : nbB;
    int* hist = dirA ? histA : histB;
    __shared__ int h[1024];
    for (int i = threadIdx.x; i < nb; i += 256) h[i] = 0;
    __syncthreads();
    int EV = E >> 2;
    int vchunk = (EV + SB_ - 1) / SB_;
    int vs = b * vchunk, ve = min(EV, vs + vchunk);
    for (int v = vs + threadIdx.x; v < ve; v += 256) {
        i32x4 d4 = __builtin_nontemporal_load(reinterpret_cast<const i32x4*>(dstp) + v);
        atomicAdd(&h[d4.x >> 6], 1);
        atomicAdd(&h[d4.y >> 6], 1);
        atomicAdd(&h[d4.z >> 6], 1);
        atomicAdd(&h[d4.w >> 6], 1);
    }
    if (b == 0) {
        int tail = E & 3;
        if ((int)threadIdx.x < tail) {
            int d = dstp[E - tail + threadIdx.x];
            atomicAdd(&h[d >> 6], 1);
        }
    }
    __syncthreads();
    for (int i = threadIdx.x; i < nb; i += 256) hist[b * nb + i] = h[i];
}

// ---------------- radix pass 2: exact offsets (no atomics needed in scatter) ----------------
__global__ __launch_bounds__(256) void radix_scan(
    const int* __restrict__ histA, const int* __restrict__ histB,
    int* __restrict__ offA, int* __restrict__ offB,
    int* __restrict__ bsA, int* __restrict__ bsB, int nbA, int nbB)
{
    __shared__ int tsum[256];
    int tid = threadIdx.x;
    for (int dir = 0; dir < 2; ++dir) {
        const int* hist = dir ? histB : histA;
        int* off = dir ? offB : offA;
        int* bs = dir ? bsB : bsA;
        int nb = dir ? nbB : nbA;
        int per = (nb + 255) >> 8;
        int b0 = tid * per;
        int loc[8];
        int lsum = 0;
        for (int k = 0; k < per; ++k) {
            int b = b0 + k;
            int t = 0;
            if (b < nb)
                for (int r = 0; r < SB_; ++r) t += hist[r * nb + b];
            loc[k] = t; lsum += t;
        }
        __syncthreads();
        tsum[tid] = lsum;
        __syncthreads();
        for (int ofs = 1; ofs < 256; ofs <<= 1) {
            int v = (tid >= ofs) ? tsum[tid - ofs] : 0;
            __syncthreads();
            tsum[tid] += v;
            __syncthreads();
        }
        int run = tid ? tsum[tid - 1] : 0;
        for (int k = 0; k < per; ++k) {
            int b = b0 + k;
            if (b < nb) {
                bs[b] = run;
                int r2 = run;
                for (int r = 0; r < SB_; ++r) {
                    off[r * nb + b] = r2;
                    r2 += hist[r * nb + b];
                }
            }
            run += loc[k];
        }
        if (tid == 255) bs[nb] = tsum[255];
        __syncthreads();
    }
}

// ---------------- radix pass 3: scatter packed (dstlow|src) into bin regions ----------------
__global__ __launch_bounds__(256) void radix_scatter(
    const int* __restrict__ e12, const int* __restrict__ e21,
    const int* __restrict__ offA, const int* __restrict__ offB,
    unsigned int* __restrict__ payA, unsigned int* __restrict__ payB,
    int E, int nbA, int nbB)
{
    int blk = blockIdx.x;
    bool dirA = blk < SB_;
    int b = dirA ? blk : blk - SB_;
    const int* srcp = dirA ? e12 : e21;
    const int* dstp = dirA ? (e12 + E) : (e21 + E);
    const int* off = dirA ? offA : offB;
    unsigned int* pay = dirA ? payA : payB;
    int nb = dirA ? nbA : nbB;
    __shared__ int offs[1024];
    for (int i = threadIdx.x; i < nb; i += 256) offs[i] = off[b * nb + i];
    __syncthreads();
    int EV = E >> 2;
    int vchunk = (EV + SB_ - 1) / SB_;
    int vs = b * vchunk, ve = min(EV, vs + vchunk);
    for (int v = vs + threadIdx.x; v < ve; v += 256) {
        i32x4 d4 = __builtin_nontemporal_load(reinterpret_cast<const i32x4*>(dstp) + v);
        i32x4 s4 = __builtin_nontemporal_load(reinterpret_cast<const i32x4*>(srcp) + v);
        int p;
        p = atomicAdd(&offs[d4.x >> 6], 1); pay[p] = (((unsigned int)(d4.x & 63)) << 16) | (unsigned int)s4.x;
        p = atomicAdd(&offs[d4.y >> 6], 1); pay[p] = (((unsigned int)(d4.y & 63)) << 16) | (unsigned int)s4.y;
        p = atomicAdd(&offs[d4.z >> 6], 1); pay[p] = (((unsigned int)(d4.z & 63)) << 16) | (unsigned int)s4.z;
        p = atomicAdd(&offs[d4.w >> 6], 1); pay[p] = (((unsigned int)(d4.w & 63)) << 16) | (unsigned int)s4.w;
    }
    if (b == 0) {
        int tail = E & 3;
        if ((int)threadIdx.x < tail) {
            int i = E - tail + threadIdx.x;
            int d = dstp[i];
            int p = atomicAdd(&offs[d >> 6], 1);
            pay[p] = (((unsigned int)(d & 63)) << 16) | (unsigned int)srcp[i];
        }
    }
}

// ---------------- radix pass 4: bin -> dense cs tile (one 8KB coalesced write) ----------------
__global__ __launch_bounds__(256) void bin_expand(
    const unsigned int* __restrict__ payA, const int* __restrict__ bsA, int nbA,
    ushort_t* __restrict__ cs12, int* __restrict__ cnt12, int NdA,
    const unsigned int* __restrict__ payB, const int* __restrict__ bsB, int nbB,
    ushort_t* __restrict__ cs21, int* __restrict__ cnt21, int NdB)
{
    int blk = blockIdx.x;
    bool dirA = blk < nbA;
    int b = dirA ? blk : blk - nbA;
    const unsigned int* pay = dirA ? payA : payB;
    const int* bs = dirA ? bsA : bsB;
    ushort_t* cs = dirA ? cs12 : cs21;
    int* cnt = dirA ? cnt12 : cnt21;
    int Nd = dirA ? NdA : NdB;
    __shared__ int c[64];
    __shared__ ushort_t list[64 * 64];
    if (threadIdx.x < 64) c[threadIdx.x] = 0;
    __syncthreads();
    int rs = bs[b], re = bs[b + 1];
    for (int i = rs + threadIdx.x; i < re; i += 256) {
        unsigned int e = pay[i];
        int dl = e >> 16;
        int pos = atomicAdd(&c[dl], 1);
        if (pos < BUCKET_CAP) list[(dl << 6) + pos] = (ushort_t)(e & 0xffff);
    }
    __syncthreads();
    int d0 = b << 6;
    int nrow = min(64, Nd - d0);
    if (nrow <= 0) return;
    const unsigned int* lsrc = reinterpret_cast<const unsigned int*>(list);
    unsigned int* gdst = reinterpret_cast<unsigned int*>(cs + ((size_t)d0 << 6));
    int nu32 = nrow << 5;
    for (int u = threadIdx.x; u < nu32; u += 256) gdst[u] = lsrc[u];
    if ((int)threadIdx.x < nrow) cnt[d0 + threadIdx.x] = c[threadIdx.x];
}

// ---------------- gather8: 4 edges/wave, fp8 KV (unchanged from round 12) ----------------
__global__ __launch_bounds__(256) void gather8_kernel(
    const int* __restrict__ cntA, const ushort_t* __restrict__ csA,
    const short* __restrict__ QA, const uchar_t* __restrict__ KVA, short* __restrict__ GA, int NA,
    const int* __restrict__ cntB, const ushort_t* __restrict__ csB,
    const short* __restrict__ QB, const uchar_t* __restrict__ KVB, short* __restrict__ GB, int NB)
{
    int grp = blockIdx.x & 7;
    int localBlock = (blockIdx.x >> 3) * 4 + (grp & 3);
    const int* cnt; const ushort_t* cs; const short* Qb; const uchar_t* KV; short* G; int N;
    if (grp < 4) { cnt = cntA; cs = csA; Qb = QA; KV = KVA; G = GA; N = NA; }
    else         { cnt = cntB; cs = csB; Qb = QB; KV = KVB; G = GB; N = NB; }
    int d = localBlock * 4 + (threadIdx.x >> 6);
    if (d >= N) return;
    int lane = threadIdx.x & 63;
    int j = lane & 15;
    int sub = lane >> 4;
    int deg = min(cnt[d], BUCKET_CAP);
    uint2 qw = *reinterpret_cast<const uint2*>(Qb + (size_t)d * 64 + 4 * j);
    float q0 = blo(qw.x), q1 = bhi(qw.x), q2 = blo(qw.y), q3 = bhi(qw.y);
    float a0 = 0.f, a1 = 0.f, a2 = 0.f, a3 = 0.f, den = 0.f;
    int idv = (lane < deg) ? (int)cs[((size_t)d << BUCKET_SHIFT) + lane] : 0;
    for (int i = 0; i < deg; i += 4) {
        int idx = i + sub;
        bool valid = idx < deg;
        int s = __shfl(idv, valid ? idx : 0);
        uint2 wv = *reinterpret_cast<const uint2*>(KV + (size_t)s * 128 + 8 * j);
        float k0 = f82f(wv.x),       v0 = f82f(wv.x >> 8);
        float k1 = f82f(wv.x >> 16), v1 = f82f(wv.x >> 24);
        float k2 = f82f(wv.y),       v2 = f82f(wv.y >> 8);
        float k3 = f82f(wv.y >> 16), v3 = f82f(wv.y >> 24);
        float t = q0 * k0;
        t = fmaf(q1, k1, t);
        t = fmaf(q2, k2, t);
        t = fmaf(q3, k3, t);
        t += __shfl_xor(t, 1);
        float e = valid ? __expf(t) : 0.f;
        den += e;
        a0 = fmaf(e, v0, a0);
        a1 = fmaf(e, v1, a1);
        a2 = fmaf(e, v2, a2);
        a3 = fmaf(e, v3, a3);
    }
    a0 += __shfl_xor(a0, 16); a1 += __shfl_xor(a1, 16);
    a2 += __shfl_xor(a2, 16); a3 += __shfl_xor(a3, 16);
    den += __shfl_xor(den, 16);
    a0 += __shfl_xor(a0, 32); a1 += __shfl_xor(a1, 32);
    a2 += __shfl_xor(a2, 32); a3 += __shfl_xor(a3, 32);
    den += __shfl_xor(den, 32);
    if (lane < 16) {
        float r = (den > 0.f) ? 1.f / den : 0.f;
        float o0 = a0 * r, o1 = a1 * r, o2 = a2 * r, o3 = a3 * r;
        float g0 = 0.5f * o0 * (1.f + erff(o0 * 0.70710678118654752f));
        float g1 = 0.5f * o1 * (1.f + erff(o1 * 0.70710678118654752f));
        float g2 = 0.5f * o2 * (1.f + erff(o2 * 0.70710678118654752f));
        float g3 = 0.5f * o3 * (1.f + erff(o3 * 0.70710678118654752f));
        uint2 pw;
        pw.x = ((unsigned int)(unsigned short)f2b(g0)) | (((unsigned int)(unsigned short)f2b(g1)) << 16);
        pw.y = ((unsigned int)(unsigned short)f2b(g2)) | (((unsigned int)(unsigned short)f2b(g3)) << 16);
        *reinterpret_cast<uint2*>(G + (size_t)d * 64 + 4 * j) = pw;
    }
}

// ---------------- fused update(l) + kqv(l+1) ----------------
__global__ __launch_bounds__(256) void updkqv_mfma(
    const short* __restrict__ G1, const short* __restrict__ Aw1, const float* __restrict__ Ab1,
    const float* __restrict__ sk1, short* __restrict__ H1, float* __restrict__ Out1, int N1,
    const short* __restrict__ G2, const short* __restrict__ Aw2, const float* __restrict__ Ab2,
    const float* __restrict__ sk2, short* __restrict__ H2, float* __restrict__ Out2, int N2,
    const short* __restrict__ Wc1n, const float* __restrict__ Bc1n,
    short* __restrict__ Q1, uchar_t* __restrict__ KV1,
    const short* __restrict__ Wc2n, const float* __restrict__ Bc2n,
    short* __restrict__ Q2, uchar_t* __restrict__ KV2,
    int nt1, int outColOff)
{
    const short* G; const short* Awb; const float* Ab; const float* skipp;
    short* Hb; float* Out; int N; int tb;
    const short* Wcat; const float* Bcat; short* Qb; uchar_t* KV;
    if (blockIdx.x < nt1) {
        G = G1; Awb = Aw1; Ab = Ab1; skipp = sk1; Hb = H1; Out = Out1; N = N1; tb = blockIdx.x;
        Wcat = Wc1n; Bcat = Bc1n; Qb = Q1; KV = KV1;
    } else {
        G = G2; Awb = Aw2; Ab = Ab2; skipp = sk2; Hb = H2; Out = Out2; N = N2; tb = blockIdx.x - nt1;
        Wcat = Wc2n; Bcat = Bc2n; Qb = Q2; KV = KV2;
    }
    __shared__ short Ws[192 * 64];
    __shared__ short hs[64][64];
    int tid = threadIdx.x;
    #pragma unroll
    for (int k = 0; k < 6; ++k) {
        int u = tid + k * 256;
        int row = u >> 3, c = u & 7;
        u32x4 v = *reinterpret_cast<const u32x4*>(Wcat + row * 64 + c * 8);
        *reinterpret_cast<u32x4*>(&Ws[row * 64 + ((c ^ (row & 7)) << 3)]) = v;
    }
    int w = tid >> 6, l = tid & 63;
    int g = l >> 4, q = l & 15;
    bf16x8 bfw[4][2];
    #pragma unroll
    for (int n = 0; n < 4; ++n)
        #pragma unroll
        for (int s = 0; s < 2; ++s)
            bfw[n][s] = *reinterpret_cast<const bf16x8*>(Awb + (n * 16 + q) * 64 + s * 32 + g * 8);
    float beta = 1.f / (1.f + __expf(-skipp[0]));
    int arow = tb * 64 + w * 16 + q;
    bool rok = arow < N;
    bf16x8 ua0 = {}, ua1 = {};
    if (rok) {
        ua0 = *reinterpret_cast<const bf16x8*>(G + (size_t)arow * 64 + g * 8);
        ua1 = *reinterpret_cast<const bf16x8*>(G + (size_t)arow * 64 + 32 + g * 8);
    }
    f32x4 uacc[4] = {};
    #pragma unroll
    for (int n = 0; n < 4; ++n) {
        uacc[n] = __builtin_amdgcn_mfma_f32_16x16x32_bf16(ua0, bfw[n][0], uacc[n], 0, 0, 0);
        uacc[n] = __builtin_amdgcn_mfma_f32_16x16x32_bf16(ua1, bfw[n][1], uacc[n], 0, 0, 0);
    }
    int orow0 = tb * 64 + w * 16 + g * 4;
    int lrow0 = w * 16 + g * 4;
    #pragma unroll
    for (int n = 0; n < 4; ++n) {
        int col = n * 16 + q;
        float bias = Ab[col];
        #pragma unroll
        for (int r = 0; r < 4; ++r) {
            int orow = orow0 + r;
            if (orow < N) {
                float hold = b2f(((const unsigned short*)Hb)[(size_t)orow * 64 + col]);
                float hnew = beta * (uacc[n][r] + bias) + (1.f - beta) * hold;
                short hb16 = f2b(hnew);
                Out[(size_t)orow * 128 + outColOff + col] = hnew;
                Hb[(size_t)orow * 64 + col] = hb16;
                hs[lrow0 + r][col] = hb16;
            } else {
                hs[lrow0 + r][col] = 0;
            }
        }
    }
    __syncthreads();
    bf16x8 a0 = *reinterpret_cast<const bf16x8*>(&hs[w * 16 + q][g * 8]);
    bf16x8 a1 = *reinterpret_cast<const bf16x8*>(&hs[w * 16 + q][32 + g * 8]);
    f32x4 acc[12] = {};
    #pragma unroll
    for (int n = 0; n < 12; ++n) {
        int br = n * 16 + q;
        bf16x8 b0 = *reinterpret_cast<bf16x8*>(&Ws[br * 64 + ((0 * 4 + g) ^ (br & 7)) * 8]);
        acc[n] = __builtin_amdgcn_mfma_f32_16x16x32_bf16(a0, b0, acc[n], 0, 0, 0);
        bf16x8 b1 = *reinterpret_cast<bf16x8*>(&Ws[br * 64 + ((1 * 4 + g) ^ (br & 7)) * 8]);
        acc[n] = __builtin_amdgcn_mfma_f32_16x16x32_bf16(a1, b1, acc[n], 0, 0, 0);
    }
    #pragma unroll
    for (int n = 0; n < 12; ++n) {
        int col = n * 16 + q;
        float bias = Bcat[col];
        #pragma unroll
        for (int r = 0; r < 4; ++r) {
            int orow = orow0 + r;
            if (orow < N) {
                float v = acc[n][r] + bias;
                if (n < 4)      Qb[(size_t)orow * 64 + col]              = f2b(v);
                else if (n < 8) KV[(size_t)orow * 128 + 2 * (col - 64)]  = f2f8(v);
                else            KV[(size_t)orow * 128 + 2 * (col - 128) + 1] = f2f8(v);
            }
        }
    }
}

// ---------------- final update ----------------
__global__ __launch_bounds__(256) void update2_mfma(
    const short* __restrict__ G1, const short* __restrict__ Aw1, const float* __restrict__ Ab1,
    const float* __restrict__ sk1, short* __restrict__ H1, float* __restrict__ Out1, int N1,
    const short* __restrict__ G2, const short* __restrict__ Aw2, const float* __restrict__ Ab2,
    const float* __restrict__ sk2, short* __restrict__ H2, float* __restrict__ Out2, int N2,
    int nt1, int outColOff)
{
    const short* G; const short* Awb; const float* Ab; const float* skipp;
    short* Hb; float* Out; int N; int tb;
    if (blockIdx.x < nt1) { G = G1; Awb = Aw1; Ab = Ab1; skipp = sk1; Hb = H1; Out = Out1; N = N1; tb = blockIdx.x; }
    else                  { G = G2; Awb = Aw2; Ab = Ab2; skipp = sk2; Hb = H2; Out = Out2; N = N2; tb = blockIdx.x - nt1; }
    int tid = threadIdx.x;
    int w = tid >> 6, l = tid & 63;
    int g = l >> 4, q = l & 15;
    bf16x8 bf[4][2];
    #pragma unroll
    for (int n = 0; n < 4; ++n)
        #pragma unroll
        for (int s = 0; s < 2; ++s)
            bf[n][s] = *reinterpret_cast<const bf16x8*>(Awb + (n * 16 + q) * 64 + s * 32 + g * 8);
    float beta = 1.f / (1.f + __expf(-skipp[0]));
    int arow = tb * 64 + w * 16 + q;
    bool rok = arow < N;
    bf16x8 a0 = {}, a1 = {};
    if (rok) {
        a0 = *reinterpret_cast<const bf16x8*>(G + (size_t)arow * 64 + g * 8);
        a1 = *reinterpret_cast<const bf16x8*>(G + (size_t)arow * 64 + 32 + g * 8);
    }
    f32x4 acc[4] = {};
    #pragma unroll
    for (int n = 0; n < 4; ++n) {
        acc[n] = __builtin_amdgcn_mfma_f32_16x16x32_bf16(a0, bf[n][0], acc[n], 0, 0, 0);
        acc[n] = __builtin_amdgcn_mfma_f32_16x16x32_bf16(a1, bf[n][1], acc[n], 0, 0, 0);
    }
    int orow0 = tb * 64 + w * 16 + g * 4;
    #pragma unroll
    for (int n = 0; n < 4; ++n) {
        int col = n * 16 + q;
        float bias = Ab[col];
        #pragma unroll
        for (int r = 0; r < 4; ++r) {
            int orow = orow0 + r;
            if (orow < N) {
                float hold = b2f(((const unsigned short*)Hb)[(size_t)orow * 64 + col]);
                float hnew = beta * (acc[n][r] + bias) + (1.f - beta) * hold;
                Out[(size_t)orow * 128 + outColOff + col] = hnew;
                Hb[(size_t)orow * 64 + col] = f2b(hnew);
            }
        }
    }
}

extern "C" void kernel_launch(void* const* d_in, const int* in_sizes, int n_in,
                              void* d_out, int out_size, void* d_ws, size_t ws_size,
                              hipStream_t stream) {
    const float* x1    = (const float*)d_in[0];
    const float* x2    = (const float*)d_in[1];
    const int*   e12   = (const int*)d_in[2];
    const int*   e21   = (const int*)d_in[3];
    const float* w_in  = (const float*)d_in[4];
    const float* b_in  = (const float*)d_in[5];
    const float* kw    = (const float*)d_in[6];
    const float* kb    = (const float*)d_in[7];
    const float* qw    = (const float*)d_in[8];
    const float* qb    = (const float*)d_in[9];
    const float* vw    = (const float*)d_in[10];
    const float* vb    = (const float*)d_in[11];
    const float* aw    = (const float*)d_in[12];
    const float* ab    = (const float*)d_in[13];
    const float* skip  = (const float*)d_in[14];
    const float* a_rel = (const float*)d_in[15];
    const float* m_rel = (const float*)d_in[16];
    const float* p_rel = (const float*)d_in[17];

    int N1 = in_sizes[0] / 256;
    int N2 = in_sizes[1] / 256;
    int E  = in_sizes[2] / 2;

    float* out = (float*)d_out;

    char* wsp = (char*)d_ws;
    auto alloc = [&](size_t bytes) { void* p = wsp; wsp += (bytes + 255) & ~(size_t)255; return p; };
    short* hb1   = (short*)alloc((size_t)N1 * 64 * 2);
    short* hb2   = (short*)alloc((size_t)N2 * 64 * 2);
    short* qb1   = (short*)alloc((size_t)N1 * 64 * 2);
    short* qb2   = (short*)alloc((size_t)N2 * 64 * 2);
    uchar_t* kv1 = (uchar_t*)alloc((size_t)N1 * 128);
    uchar_t* kv2 = (uchar_t*)alloc((size_t)N2 * 128);
    short* g1    = (short*)alloc((size_t)N1 * 64 * 2);
    short* g2    = (short*)alloc((size_t)N2 * 64 * 2);
    short* wstem = (short*)alloc(2 * 16384 * 2);
    short* WcatB = (short*)alloc(4 * 12288 * 2);
    float* BcatB = (float*)alloc(4 * 192 * 4);
    short* AwbB  = (short*)alloc(4 * 4096 * 2);
    int* cnt12   = (int*)alloc((size_t)N2 * 4);
    int* cnt21   = (int*)alloc((size_t)N1 * 4);
    ushort_t* csr12 = (ushort_t*)alloc(((size_t)N2 << BUCKET_SHIFT) * 2);
    ushort_t* csr21 = (ushort_t*)alloc(((size_t)N1 << BUCKET_SHIFT) * 2);

    int nbA = (N2 + 63) >> 6;
    int nbB = (N1 + 63) >> 6;
    int* histA = (int*)alloc((size_t)SB_ * nbA * 4);
    int* histB = (int*)alloc((size_t)SB_ * nbB * 4);
    int* offA  = (int*)alloc((size_t)SB_ * nbA * 4);
    int* offB  = (int*)alloc((size_t)SB_ * nbB * 4);
    int* bsA   = (int*)alloc((size_t)(nbA + 1) * 4);
    int* bsB   = (int*)alloc((size_t)(nbB + 1) * 4);
    unsigned int* payA = (unsigned int*)alloc((size_t)E * 4);
    unsigned int* payB = (unsigned int*)alloc((size_t)E * 4);

    const int BLK = 256;
    int nt1 = (N1 + 63) / 64;
    int nt2 = (N2 + 63) / 64;

    prep_kernel<<<6, BLK, 0, stream>>>(w_in, kw, kb, qw, qb, vw, vb, aw,
                                       a_rel, m_rel, p_rel, wstem, WcatB, BcatB, AwbB);

    radix_hist<<<2 * SB_, BLK, 0, stream>>>(e12, e21, histA, histB, E, nbA, nbB);
    radix_scan<<<1, BLK, 0, stream>>>(histA, histB, offA, offB, bsA, bsB, nbA, nbB);
    radix_scatter<<<2 * SB_, BLK, 0, stream>>>(e12, e21, offA, offB, payA, payB, E, nbA, nbB);
    bin_expand<<<nbA + nbB, BLK, 0, stream>>>(payA, bsA, nbA, csr12, cnt12, N2,
                                              payB, bsB, nbB, csr21, cnt21, N1);

    stem2_mfma<<<nt1 + nt2, BLK, 0, stream>>>(x1, x2, wstem, b_in, b_in + 64,
                                              hb1, hb2, N1, N2, nt1);

    int bA = (N2 + 3) / 4;
    int bB = (N1 + 3) / 4;
    int bmax = bA > bB ? bA : bB;
    int nlb = (bmax + 3) / 4;
    int gblocks = 8 * nlb;

    // ---- layer 0 ----
    kqv2_mfma<<<nt1 + nt2, BLK, 0, stream>>>(
        hb1, WcatB + (size_t)0 * 12288, BcatB + (size_t)0 * 192, qb1, kv1, N1,
        hb2, WcatB + (size_t)1 * 12288, BcatB + (size_t)1 * 192, qb2, kv2, N2, nt1);

    gather8_kernel<<<gblocks, BLK, 0, stream>>>(
        cnt12, csr12, qb2, kv1, g2, N2,
        cnt21, csr21, qb1, kv2, g1, N1);

    updkqv_mfma<<<nt1 + nt2, BLK, 0, stream>>>(
        g1, AwbB + (size_t)0 * 4096, ab + (size_t)0 * 64, skip + 0, hb1, out, N1,
        g2, AwbB + (size_t)1 * 4096, ab + (size_t)1 * 64, skip + 1, hb2,
        out + (size_t)N1 * 128, N2,
        WcatB + (size_t)2 * 12288, BcatB + (size_t)2 * 192, qb1, kv1,
        WcatB + (size_t)3 * 12288, BcatB + (size_t)3 * 192, qb2, kv2,
        nt1, 0);

    // ---- layer 1 ----
    gather8_kernel<<<gblocks, BLK, 0, stream>>>(
        cnt12, csr12, qb2, kv1, g2, N2,
        cnt21, csr21, qb1, kv2, g1, N1);

    update2_mfma<<<nt1 + nt2, BLK, 0, stream>>>(
        g1, AwbB + (size_t)2 * 4096, ab + (size_t)2 * 64, skip + 2, hb1, out, N1,
        g2, AwbB + (size_t)3 * 4096, ab + (size_t)3 * 64, skip + 3, hb2,
        out + (size_t)N1 * 128, N2, nt1, 64);
}

// Round 14
// 296.323 us; speedup vs baseline: 1.1921x; 1.1921x over previous
//
#include <hip/hip_runtime.h>
#include <hip/hip_bf16.h>
#include <hip/hip_fp8.h>
#include <math.h>

typedef __attribute__((ext_vector_type(8))) short bf16x8;
typedef __attribute__((ext_vector_type(4))) float f32x4;
typedef __attribute__((ext_vector_type(2))) float f32x2;
typedef __attribute__((ext_vector_type(4))) unsigned int u32x4;
typedef __attribute__((ext_vector_type(4))) int i32x4;
typedef unsigned short ushort_t;
typedef unsigned char uchar_t;

#define BUCKET_SHIFT 6
#define BUCKET_CAP   64

__device__ inline short f2b(float f) {
    __hip_bfloat16 h = __float2bfloat16(f);
    return __builtin_bit_cast(short, h);
}
__device__ inline float b2f(unsigned short u) {
    return __builtin_bit_cast(float, (unsigned int)u << 16);
}
__device__ inline float blo(unsigned int w) {
    return __builtin_bit_cast(float, w << 16);
}
__device__ inline float bhi(unsigned int w) {
    return __builtin_bit_cast(float, w & 0xffff0000u);
}
__device__ inline uchar_t f2f8(float f) {
    __hip_fp8_e4m3 h(f);
    return (uchar_t)h.__x;
}
__device__ inline float gelu1(float o) {
    return 0.5f * o * (1.f + erff(o * 0.70710678118654752f));
}

// ---------------- prep: fold rel-projections into weights, cast to bf16 ----------------
__global__ __launch_bounds__(256) void prep_kernel(
    const float* __restrict__ w_in,
    const float* __restrict__ kw, const float* __restrict__ kb,
    const float* __restrict__ qw, const float* __restrict__ qb,
    const float* __restrict__ vw, const float* __restrict__ vb,
    const float* __restrict__ aw,
    const float* __restrict__ a_rel, const float* __restrict__ m_rel,
    const float* __restrict__ p_rel,
    short* __restrict__ wstem, short* __restrict__ Wcat,
    float* __restrict__ Bcat, short* __restrict__ Awb)
{
    int bid = blockIdx.x, tid = threadIdx.x;
    if (bid >= 4) {
        int t = bid - 4;
        for (int i = tid; i < 16384; i += 256)
            wstem[t * 16384 + i] = f2b(w_in[t * 16384 + i]);
        return;
    }
    int base = bid;
    const float* KW = kw + base * 4096;
    const float* QW = qw + base * 4096;
    const float* VW = vw + base * 4096;
    const float* AR = a_rel + base * 512;
    const float* MR = m_rel + base * 512;
    const float* PR = p_rel + base * 8;
    short* WC = Wcat + base * 12288;
    float* BC = Bcat + base * 192;

    for (int i = tid; i < 4096; i += 256) WC[i] = f2b(QW[i]);
    for (int i = tid; i < 4096; i += 256) {
        int out = i >> 6, in = i & 63;
        int h = out >> 3, e = out & 7;
        float s = PR[h] * 0.35355339059327373f;
        float acc = 0.f;
        #pragma unroll
        for (int d = 0; d < 8; ++d) acc += KW[(h * 8 + d) * 64 + in] * AR[h * 64 + d * 8 + e];
        WC[4096 + i] = f2b(acc * s);
    }
    for (int i = tid; i < 4096; i += 256) {
        int out = i >> 6, in = i & 63;
        int h = out >> 3, e = out & 7;
        float acc = 0.f;
        #pragma unroll
        for (int d = 0; d < 8; ++d) acc += VW[(h * 8 + d) * 64 + in] * MR[h * 64 + d * 8 + e];
        WC[8192 + i] = f2b(acc);
    }
    if (tid < 64) {
        BC[tid] = qb[base * 64 + tid];
    } else if (tid < 128) {
        int out = tid - 64;
        int h = out >> 3, e = out & 7;
        float s = PR[h] * 0.35355339059327373f;
        float acc = 0.f;
        #pragma unroll
        for (int d = 0; d < 8; ++d) acc += kb[base * 64 + h * 8 + d] * AR[h * 64 + d * 8 + e];
        BC[64 + out] = acc * s;
    } else if (tid < 192) {
        int out = tid - 128;
        int h = out >> 3, e = out & 7;
        float acc = 0.f;
        #pragma unroll
        for (int d = 0; d < 8; ++d) acc += vb[base * 64 + h * 8 + d] * MR[h * 64 + d * 8 + e];
        BC[128 + out] = acc;
    }
    for (int i = tid; i < 4096; i += 256) Awb[base * 4096 + i] = f2b(aw[base * 4096 + i]);
}

// ---------------- merged stem ----------------
__global__ __launch_bounds__(256) void stem2_mfma(
    const float* __restrict__ X1, const float* __restrict__ X2,
    const short* __restrict__ Wb, const float* __restrict__ B1, const float* __restrict__ B2,
    short* __restrict__ H1, short* __restrict__ H2, int N1, int N2, int nt1)
{
    const float* X; const short* Wsrc; const float* B; short* Hb; int N; int tb;
    if (blockIdx.x < nt1) { X = X1; Wsrc = Wb;         B = B1; Hb = H1; N = N1; tb = blockIdx.x; }
    else                  { X = X2; Wsrc = Wb + 16384; B = B2; Hb = H2; N = N2; tb = blockIdx.x - nt1; }
    __shared__ short Ws[64 * 256];
    int tid = threadIdx.x;
    #pragma unroll
    for (int k = 0; k < 8; ++k) {
        int u = tid + k * 256;
        int row = u >> 5, c = u & 31;
        u32x4 v = *reinterpret_cast<const u32x4*>(Wsrc + row * 256 + c * 8);
        *reinterpret_cast<u32x4*>(&Ws[row * 256 + ((c ^ (row & 7)) << 3)]) = v;
    }
    __syncthreads();
    int w = tid >> 6, l = tid & 63;
    int g = l >> 4, q = l & 15;
    int row = tb * 64 + w * 16 + q;
    bool rok = row < N;
    f32x4 acc[4] = {};
    const float* xr = X + (size_t)row * 256 + g * 8;
    #pragma unroll
    for (int s = 0; s < 8; ++s) {
        bf16x8 a = {};
        if (rok) {
            float4 x0 = *reinterpret_cast<const float4*>(xr + s * 32);
            float4 x1 = *reinterpret_cast<const float4*>(xr + s * 32 + 4);
            a[0] = f2b(x0.x); a[1] = f2b(x0.y); a[2] = f2b(x0.z); a[3] = f2b(x0.w);
            a[4] = f2b(x1.x); a[5] = f2b(x1.y); a[6] = f2b(x1.z); a[7] = f2b(x1.w);
        }
        #pragma unroll
        for (int n = 0; n < 4; ++n) {
            int br = n * 16 + q;
            int c = s * 4 + g;
            bf16x8 b = *reinterpret_cast<bf16x8*>(&Ws[br * 256 + ((c ^ (br & 7)) << 3)]);
            acc[n] = __builtin_amdgcn_mfma_f32_16x16x32_bf16(a, b, acc[n], 0, 0, 0);
        }
    }
    int orow0 = tb * 64 + w * 16 + g * 4;
    #pragma unroll
    for (int n = 0; n < 4; ++n) {
        int col = n * 16 + q;
        float bias = B[col];
        #pragma unroll
        for (int r = 0; r < 4; ++r) {
            int orow = orow0 + r;
            if (orow < N)
                Hb[(size_t)orow * 64 + col] = f2b(fmaxf(acc[n][r] + bias, 0.f));
        }
    }
}

// ---------------- kqv: q bf16, KV fp8 interleaved ----------------
__global__ __launch_bounds__(256) void kqv2_mfma(
    const short* __restrict__ H1, const short* __restrict__ Wc1, const float* __restrict__ Bc1,
    short* __restrict__ Q1, uchar_t* __restrict__ KV1, int N1,
    const short* __restrict__ H2, const short* __restrict__ Wc2, const float* __restrict__ Bc2,
    short* __restrict__ Q2, uchar_t* __restrict__ KV2, int N2, int nt1)
{
    const short* Hb; const short* Wcat; const float* Bcat; short* Qb; uchar_t* KV; int N; int tb;
    if (blockIdx.x < nt1) { Hb = H1; Wcat = Wc1; Bcat = Bc1; Qb = Q1; KV = KV1; N = N1; tb = blockIdx.x; }
    else                  { Hb = H2; Wcat = Wc2; Bcat = Bc2; Qb = Q2; KV = KV2; N = N2; tb = blockIdx.x - nt1; }
    __shared__ short Ws[192 * 64];
    int tid = threadIdx.x;
    #pragma unroll
    for (int k = 0; k < 6; ++k) {
        int u = tid + k * 256;
        int row = u >> 3, c = u & 7;
        u32x4 v = *reinterpret_cast<const u32x4*>(Wcat + row * 64 + c * 8);
        *reinterpret_cast<u32x4*>(&Ws[row * 64 + ((c ^ (row & 7)) << 3)]) = v;
    }
    __syncthreads();
    int w = tid >> 6, l = tid & 63;
    int g = l >> 4, q = l & 15;
    int arow = tb * 64 + w * 16 + q;
    bool rok = arow < N;
    bf16x8 a0 = {}, a1 = {};
    if (rok) {
        a0 = *reinterpret_cast<const bf16x8*>(Hb + (size_t)arow * 64 + g * 8);
        a1 = *reinterpret_cast<const bf16x8*>(Hb + (size_t)arow * 64 + 32 + g * 8);
    }
    f32x4 acc[12] = {};
    #pragma unroll
    for (int n = 0; n < 12; ++n) {
        int br = n * 16 + q;
        bf16x8 b0 = *reinterpret_cast<bf16x8*>(&Ws[br * 64 + ((0 * 4 + g) ^ (br & 7)) * 8]);
        acc[n] = __builtin_amdgcn_mfma_f32_16x16x32_bf16(a0, b0, acc[n], 0, 0, 0);
        bf16x8 b1 = *reinterpret_cast<bf16x8*>(&Ws[br * 64 + ((1 * 4 + g) ^ (br & 7)) * 8]);
        acc[n] = __builtin_amdgcn_mfma_f32_16x16x32_bf16(a1, b1, acc[n], 0, 0, 0);
    }
    int orow0 = tb * 64 + w * 16 + g * 4;
    #pragma unroll
    for (int n = 0; n < 12; ++n) {
        int col = n * 16 + q;
        float bias = Bcat[col];
        #pragma unroll
        for (int r = 0; r < 4; ++r) {
            int orow = orow0 + r;
            if (orow < N) {
                float v = acc[n][r] + bias;
                if (n < 4)      Qb[(size_t)orow * 64 + col]              = f2b(v);
                else if (n < 8) KV[(size_t)orow * 128 + 2 * (col - 64)]  = f2f8(v);
                else            KV[(size_t)orow * 128 + 2 * (col - 128) + 1] = f2f8(v);
            }
        }
    }
}

// ---------------- bucket build: direction-split XCD groups (round-12 known-good) ----------------
__global__ __launch_bounds__(256) void bucket8d_kernel(
    const int* __restrict__ e12, const int* __restrict__ e21,
    int* __restrict__ cnt12, int* __restrict__ cnt21,
    ushort_t* __restrict__ cs12, ushort_t* __restrict__ cs21,
    int E, int N1, int N2, int G)
{
    int grp = blockIdx.x & 7;
    int blk = blockIdx.x >> 3;
    bool dirA = grp < 4;
    const int* srcp = dirA ? e12 : e21;
    const int* dstp = dirA ? (e12 + E) : (e21 + E);
    int* cnt = dirA ? cnt12 : cnt21;
    ushort_t* cs = dirA ? cs12 : cs21;
    int Nn = dirA ? N2 : N1;
    int qr = grp & 3;
    int range = (Nn + 3) >> 2;
    int lo = qr * range, hi = lo + range;
    int E4 = E >> 2;
    int stride = G * 256;
    for (int v = blk * 256 + threadIdx.x; v < E4; v += stride) {
        i32x4 d4 = __builtin_nontemporal_load(reinterpret_cast<const i32x4*>(dstp) + v);
        int base = v * 4;
        if (d4.x >= lo && d4.x < hi) { int p = atomicAdd(&cnt[d4.x], 1); if (p < BUCKET_CAP) cs[((size_t)d4.x << BUCKET_SHIFT) + p] = (ushort_t)srcp[base]; }
        if (d4.y >= lo && d4.y < hi) { int p = atomicAdd(&cnt[d4.y], 1); if (p < BUCKET_CAP) cs[((size_t)d4.y << BUCKET_SHIFT) + p] = (ushort_t)srcp[base + 1]; }
        if (d4.z >= lo && d4.z < hi) { int p = atomicAdd(&cnt[d4.z], 1); if (p < BUCKET_CAP) cs[((size_t)d4.z << BUCKET_SHIFT) + p] = (ushort_t)srcp[base + 2]; }
        if (d4.w >= lo && d4.w < hi) { int p = atomicAdd(&cnt[d4.w], 1); if (p < BUCKET_CAP) cs[((size_t)d4.w << BUCKET_SHIFT) + p] = (ushort_t)srcp[base + 3]; }
    }
    int tail = E & 3;
    if (blk == 0 && threadIdx.x < tail) {
        int i = E - tail + threadIdx.x;
        int d = dstp[i];
        if (d >= lo && d < hi) { int p = atomicAdd(&cnt[d], 1); if (p < BUCKET_CAP) cs[((size_t)d << BUCKET_SHIFT) + p] = (ushort_t)srcp[i]; }
    }
}

// ---------------- gather64: 8 edges/wave, lane = (sub, head); lane-local head dot ----------------
// KV row = 128B; head j's 8 (k,v) fp8 pairs = bytes 16j..16j+15 -> one uint4 per lane-edge.
// HW packed decode: cvt_pk_f32_fp8 (2 fp8 -> 2 f32 per inst).
__global__ __launch_bounds__(256) void gather64_kernel(
    const int* __restrict__ cntA, const ushort_t* __restrict__ csA,
    const short* __restrict__ QA, const uchar_t* __restrict__ KVA, short* __restrict__ GA, int NA,
    const int* __restrict__ cntB, const ushort_t* __restrict__ csB,
    const short* __restrict__ QB, const uchar_t* __restrict__ KVB, short* __restrict__ GB, int NB)
{
    int grp = blockIdx.x & 7;
    int localBlock = (blockIdx.x >> 3) * 4 + (grp & 3);
    const int* cnt; const ushort_t* cs; const short* Qb; const uchar_t* KV; short* G; int N;
    if (grp < 4) { cnt = cntA; cs = csA; Qb = QA; KV = KVA; G = GA; N = NA; }
    else         { cnt = cntB; cs = csB; Qb = QB; KV = KVB; G = GB; N = NB; }
    int d = localBlock * 4 + (threadIdx.x >> 6);
    if (d >= N) return;
    int lane = threadIdx.x & 63;
    int j = lane & 7;           // head
    int sub = lane >> 3;        // edge slot 0-7
    int deg = min(cnt[d], BUCKET_CAP);
    // q for head j: 8 bf16 dims = 16B
    u32x4 qw = *reinterpret_cast<const u32x4*>(Qb + (size_t)d * 64 + 8 * j);
    float q0 = blo(qw.x), q1 = bhi(qw.x), q2 = blo(qw.y), q3 = bhi(qw.y);
    float q4 = blo(qw.z), q5 = bhi(qw.z), q6 = blo(qw.w), q7 = bhi(qw.w);
    float a0 = 0.f, a1 = 0.f, a2 = 0.f, a3 = 0.f;
    float a4 = 0.f, a5 = 0.f, a6 = 0.f, a7 = 0.f, den = 0.f;
    int idv = (lane < deg) ? (int)cs[((size_t)d << BUCKET_SHIFT) + lane] : 0;
    for (int i = 0; i < deg; i += 8) {
        int idx = i + sub;
        bool valid = idx < deg;
        int s = __shfl(idv, valid ? idx : 0);
        u32x4 wv = *reinterpret_cast<const u32x4*>(KV + (size_t)s * 128 + 16 * j);
        f32x2 p0 = __builtin_amdgcn_cvt_pk_f32_fp8((int)wv.x, false);   // k0, v0
        f32x2 p1 = __builtin_amdgcn_cvt_pk_f32_fp8((int)wv.x, true);    // k1, v1
        f32x2 p2 = __builtin_amdgcn_cvt_pk_f32_fp8((int)wv.y, false);
        f32x2 p3 = __builtin_amdgcn_cvt_pk_f32_fp8((int)wv.y, true);
        f32x2 p4 = __builtin_amdgcn_cvt_pk_f32_fp8((int)wv.z, false);
        f32x2 p5 = __builtin_amdgcn_cvt_pk_f32_fp8((int)wv.z, true);
        f32x2 p6 = __builtin_amdgcn_cvt_pk_f32_fp8((int)wv.w, false);
        f32x2 p7 = __builtin_amdgcn_cvt_pk_f32_fp8((int)wv.w, true);
        float t = q0 * p0[0];
        t = fmaf(q1, p1[0], t);
        t = fmaf(q2, p2[0], t);
        t = fmaf(q3, p3[0], t);
        t = fmaf(q4, p4[0], t);
        t = fmaf(q5, p5[0], t);
        t = fmaf(q6, p6[0], t);
        t = fmaf(q7, p7[0], t);
        float e = valid ? __expf(t) : 0.f;
        den += e;
        a0 = fmaf(e, p0[1], a0);
        a1 = fmaf(e, p1[1], a1);
        a2 = fmaf(e, p2[1], a2);
        a3 = fmaf(e, p3[1], a3);
        a4 = fmaf(e, p4[1], a4);
        a5 = fmaf(e, p5[1], a5);
        a6 = fmaf(e, p6[1], a6);
        a7 = fmaf(e, p7[1], a7);
    }
    // reduce over sub (lane bits 3-5)
    #pragma unroll
    for (int m = 8; m <= 32; m <<= 1) {
        a0 += __shfl_xor(a0, m); a1 += __shfl_xor(a1, m);
        a2 += __shfl_xor(a2, m); a3 += __shfl_xor(a3, m);
        a4 += __shfl_xor(a4, m); a5 += __shfl_xor(a5, m);
        a6 += __shfl_xor(a6, m); a7 += __shfl_xor(a7, m);
        den += __shfl_xor(den, m);
    }
    if (lane < 8) {
        float r = (den > 0.f) ? 1.f / den : 0.f;
        float g0 = gelu1(a0 * r), g1 = gelu1(a1 * r), g2 = gelu1(a2 * r), g3 = gelu1(a3 * r);
        float g4 = gelu1(a4 * r), g5 = gelu1(a5 * r), g6 = gelu1(a6 * r), g7 = gelu1(a7 * r);
        u32x4 pw;
        pw.x = ((unsigned int)(unsigned short)f2b(g0)) | (((unsigned int)(unsigned short)f2b(g1)) << 16);
        pw.y = ((unsigned int)(unsigned short)f2b(g2)) | (((unsigned int)(unsigned short)f2b(g3)) << 16);
        pw.z = ((unsigned int)(unsigned short)f2b(g4)) | (((unsigned int)(unsigned short)f2b(g5)) << 16);
        pw.w = ((unsigned int)(unsigned short)f2b(g6)) | (((unsigned int)(unsigned short)f2b(g7)) << 16);
        *reinterpret_cast<u32x4*>(G + (size_t)d * 64 + 8 * j) = pw;
    }
}

// ---------------- fused update(l) + kqv(l+1) ----------------
__global__ __launch_bounds__(256) void updkqv_mfma(
    const short* __restrict__ G1, const short* __restrict__ Aw1, const float* __restrict__ Ab1,
    const float* __restrict__ sk1, short* __restrict__ H1, float* __restrict__ Out1, int N1,
    const short* __restrict__ G2, const short* __restrict__ Aw2, const float* __restrict__ Ab2,
    const float* __restrict__ sk2, short* __restrict__ H2, float* __restrict__ Out2, int N2,
    const short* __restrict__ Wc1n, const float* __restrict__ Bc1n,
    short* __restrict__ Q1, uchar_t* __restrict__ KV1,
    const short* __restrict__ Wc2n, const float* __restrict__ Bc2n,
    short* __restrict__ Q2, uchar_t* __restrict__ KV2,
    int nt1, int outColOff)
{
    const short* G; const short* Awb; const float* Ab; const float* skipp;
    short* Hb; float* Out; int N; int tb;
    const short* Wcat; const float* Bcat; short* Qb; uchar_t* KV;
    if (blockIdx.x < nt1) {
        G = G1; Awb = Aw1; Ab = Ab1; skipp = sk1; Hb = H1; Out = Out1; N = N1; tb = blockIdx.x;
        Wcat = Wc1n; Bcat = Bc1n; Qb = Q1; KV = KV1;
    } else {
        G = G2; Awb = Aw2; Ab = Ab2; skipp = sk2; Hb = H2; Out = Out2; N = N2; tb = blockIdx.x - nt1;
        Wcat = Wc2n; Bcat = Bc2n; Qb = Q2; KV = KV2;
    }
    __shared__ short Ws[192 * 64];
    __shared__ short hs[64][64];
    int tid = threadIdx.x;
    #pragma unroll
    for (int k = 0; k < 6; ++k) {
        int u = tid + k * 256;
        int row = u >> 3, c = u & 7;
        u32x4 v = *reinterpret_cast<const u32x4*>(Wcat + row * 64 + c * 8);
        *reinterpret_cast<u32x4*>(&Ws[row * 64 + ((c ^ (row & 7)) << 3)]) = v;
    }
    int w = tid >> 6, l = tid & 63;
    int g = l >> 4, q = l & 15;
    bf16x8 bfw[4][2];
    #pragma unroll
    for (int n = 0; n < 4; ++n)
        #pragma unroll
        for (int s = 0; s < 2; ++s)
            bfw[n][s] = *reinterpret_cast<const bf16x8*>(Awb + (n * 16 + q) * 64 + s * 32 + g * 8);
    float beta = 1.f / (1.f + __expf(-skipp[0]));
    int arow = tb * 64 + w * 16 + q;
    bool rok = arow < N;
    bf16x8 ua0 = {}, ua1 = {};
    if (rok) {
        ua0 = *reinterpret_cast<const bf16x8*>(G + (size_t)arow * 64 + g * 8);
        ua1 = *reinterpret_cast<const bf16x8*>(G + (size_t)arow * 64 + 32 + g * 8);
    }
    f32x4 uacc[4] = {};
    #pragma unroll
    for (int n = 0; n < 4; ++n) {
        uacc[n] = __builtin_amdgcn_mfma_f32_16x16x32_bf16(ua0, bfw[n][0], uacc[n], 0, 0, 0);
        uacc[n] = __builtin_amdgcn_mfma_f32_16x16x32_bf16(ua1, bfw[n][1], uacc[n], 0, 0, 0);
    }
    int orow0 = tb * 64 + w * 16 + g * 4;
    int lrow0 = w * 16 + g * 4;
    #pragma unroll
    for (int n = 0; n < 4; ++n) {
        int col = n * 16 + q;
        float bias = Ab[col];
        #pragma unroll
        for (int r = 0; r < 4; ++r) {
            int orow = orow0 + r;
            if (orow < N) {
                float hold = b2f(((const unsigned short*)Hb)[(size_t)orow * 64 + col]);
                float hnew = beta * (uacc[n][r] + bias) + (1.f - beta) * hold;
                short hb16 = f2b(hnew);
                Out[(size_t)orow * 128 + outColOff + col] = hnew;
                Hb[(size_t)orow * 64 + col] = hb16;
                hs[lrow0 + r][col] = hb16;
            } else {
                hs[lrow0 + r][col] = 0;
            }
        }
    }
    __syncthreads();
    bf16x8 a0 = *reinterpret_cast<const bf16x8*>(&hs[w * 16 + q][g * 8]);
    bf16x8 a1 = *reinterpret_cast<const bf16x8*>(&hs[w * 16 + q][32 + g * 8]);
    f32x4 acc[12] = {};
    #pragma unroll
    for (int n = 0; n < 12; ++n) {
        int br = n * 16 + q;
        bf16x8 b0 = *reinterpret_cast<bf16x8*>(&Ws[br * 64 + ((0 * 4 + g) ^ (br & 7)) * 8]);
        acc[n] = __builtin_amdgcn_mfma_f32_16x16x32_bf16(a0, b0, acc[n], 0, 0, 0);
        bf16x8 b1 = *reinterpret_cast<bf16x8*>(&Ws[br * 64 + ((1 * 4 + g) ^ (br & 7)) * 8]);
        acc[n] = __builtin_amdgcn_mfma_f32_16x16x32_bf16(a1, b1, acc[n], 0, 0, 0);
    }
    #pragma unroll
    for (int n = 0; n < 12; ++n) {
        int col = n * 16 + q;
        float bias = Bcat[col];
        #pragma unroll
        for (int r = 0; r < 4; ++r) {
            int orow = orow0 + r;
            if (orow < N) {
                float v = acc[n][r] + bias;
                if (n < 4)      Qb[(size_t)orow * 64 + col]              = f2b(v);
                else if (n < 8) KV[(size_t)orow * 128 + 2 * (col - 64)]  = f2f8(v);
                else            KV[(size_t)orow * 128 + 2 * (col - 128) + 1] = f2f8(v);
            }
        }
    }
}

// ---------------- final update ----------------
__global__ __launch_bounds__(256) void update2_mfma(
    const short* __restrict__ G1, const short* __restrict__ Aw1, const float* __restrict__ Ab1,
    const float* __restrict__ sk1, short* __restrict__ H1, float* __restrict__ Out1, int N1,
    const short* __restrict__ G2, const short* __restrict__ Aw2, const float* __restrict__ Ab2,
    const float* __restrict__ sk2, short* __restrict__ H2, float* __restrict__ Out2, int N2,
    int nt1, int outColOff)
{
    const short* G; const short* Awb; const float* Ab; const float* skipp;
    short* Hb; float* Out; int N; int tb;
    if (blockIdx.x < nt1) { G = G1; Awb = Aw1; Ab = Ab1; skipp = sk1; Hb = H1; Out = Out1; N = N1; tb = blockIdx.x; }
    else                  { G = G2; Awb = Aw2; Ab = Ab2; skipp = sk2; Hb = H2; Out = Out2; N = N2; tb = blockIdx.x - nt1; }
    int tid = threadIdx.x;
    int w = tid >> 6, l = tid & 63;
    int g = l >> 4, q = l & 15;
    bf16x8 bf[4][2];
    #pragma unroll
    for (int n = 0; n < 4; ++n)
        #pragma unroll
        for (int s = 0; s < 2; ++s)
            bf[n][s] = *reinterpret_cast<const bf16x8*>(Awb + (n * 16 + q) * 64 + s * 32 + g * 8);
    float beta = 1.f / (1.f + __expf(-skipp[0]));
    int arow = tb * 64 + w * 16 + q;
    bool rok = arow < N;
    bf16x8 a0 = {}, a1 = {};
    if (rok) {
        a0 = *reinterpret_cast<const bf16x8*>(G + (size_t)arow * 64 + g * 8);
        a1 = *reinterpret_cast<const bf16x8*>(G + (size_t)arow * 64 + 32 + g * 8);
    }
    f32x4 acc[4] = {};
    #pragma unroll
    for (int n = 0; n < 4; ++n) {
        acc[n] = __builtin_amdgcn_mfma_f32_16x16x32_bf16(a0, bf[n][0], acc[n], 0, 0, 0);
        acc[n] = __builtin_amdgcn_mfma_f32_16x16x32_bf16(a1, bf[n][1], acc[n], 0, 0, 0);
    }
    int orow0 = tb * 64 + w * 16 + g * 4;
    #pragma unroll
    for (int n = 0; n < 4; ++n) {
        int col = n * 16 + q;
        float bias = Ab[col];
        #pragma unroll
        for (int r = 0; r < 4; ++r) {
            int orow = orow0 + r;
            if (orow < N) {
                float hold = b2f(((const unsigned short*)Hb)[(size_t)orow * 64 + col]);
                float hnew = beta * (acc[n][r] + bias) + (1.f - beta) * hold;
                Out[(size_t)orow * 128 + outColOff + col] = hnew;
                Hb[(size_t)orow * 64 + col] = f2b(hnew);
            }
        }
    }
}

extern "C" void kernel_launch(void* const* d_in, const int* in_sizes, int n_in,
                              void* d_out, int out_size, void* d_ws, size_t ws_size,
                              hipStream_t stream) {
    const float* x1    = (const float*)d_in[0];
    const float* x2    = (const float*)d_in[1];
    const int*   e12   = (const int*)d_in[2];
    const int*   e21   = (const int*)d_in[3];
    const float* w_in  = (const float*)d_in[4];
    const float* b_in  = (const float*)d_in[5];
    const float* kw    = (const float*)d_in[6];
    const float* kb    = (const float*)d_in[7];
    const float* qw    = (const float*)d_in[8];
    const float* qb    = (const float*)d_in[9];
    const float* vw    = (const float*)d_in[10];
    const float* vb    = (const float*)d_in[11];
    const float* aw    = (const float*)d_in[12];
    const float* ab    = (const float*)d_in[13];
    const float* skip  = (const float*)d_in[14];
    const float* a_rel = (const float*)d_in[15];
    const float* m_rel = (const float*)d_in[16];
    const float* p_rel = (const float*)d_in[17];

    int N1 = in_sizes[0] / 256;
    int N2 = in_sizes[1] / 256;
    int E  = in_sizes[2] / 2;

    float* out = (float*)d_out;

    char* wsp = (char*)d_ws;
    auto alloc = [&](size_t bytes) { void* p = wsp; wsp += (bytes + 255) & ~(size_t)255; return p; };
    short* hb1   = (short*)alloc((size_t)N1 * 64 * 2);
    short* hb2   = (short*)alloc((size_t)N2 * 64 * 2);
    short* qb1   = (short*)alloc((size_t)N1 * 64 * 2);
    short* qb2   = (short*)alloc((size_t)N2 * 64 * 2);
    uchar_t* kv1 = (uchar_t*)alloc((size_t)N1 * 128);
    uchar_t* kv2 = (uchar_t*)alloc((size_t)N2 * 128);
    short* g1    = (short*)alloc((size_t)N1 * 64 * 2);
    short* g2    = (short*)alloc((size_t)N2 * 64 * 2);
    short* wstem = (short*)alloc(2 * 16384 * 2);
    short* WcatB = (short*)alloc(4 * 12288 * 2);
    float* BcatB = (float*)alloc(4 * 192 * 4);
    short* AwbB  = (short*)alloc(4 * 4096 * 2);
    int* cnts    = (int*)alloc((size_t)(N1 + N2) * 4);
    int* cnt12   = cnts;
    int* cnt21   = cnts + N2;
    ushort_t* csr12 = (ushort_t*)alloc(((size_t)N2 << BUCKET_SHIFT) * 2);
    ushort_t* csr21 = (ushort_t*)alloc(((size_t)N1 << BUCKET_SHIFT) * 2);

    const int BLK = 256;
    int nt1 = (N1 + 63) / 64;
    int nt2 = (N2 + 63) / 64;
    const int G8 = 512;

    prep_kernel<<<6, BLK, 0, stream>>>(w_in, kw, kb, qw, qb, vw, vb, aw,
                                       a_rel, m_rel, p_rel, wstem, WcatB, BcatB, AwbB);

    hipMemsetAsync(cnts, 0, (size_t)(N1 + N2) * 4, stream);
    bucket8d_kernel<<<8 * G8, BLK, 0, stream>>>(e12, e21, cnt12, cnt21,
                                                csr12, csr21, E, N1, N2, G8);

    stem2_mfma<<<nt1 + nt2, BLK, 0, stream>>>(x1, x2, wstem, b_in, b_in + 64,
                                              hb1, hb2, N1, N2, nt1);

    int bA = (N2 + 3) / 4;
    int bB = (N1 + 3) / 4;
    int bmax = bA > bB ? bA : bB;
    int nlb = (bmax + 3) / 4;
    int gblocks = 8 * nlb;

    // ---- layer 0 ----
    kqv2_mfma<<<nt1 + nt2, BLK, 0, stream>>>(
        hb1, WcatB + (size_t)0 * 12288, BcatB + (size_t)0 * 192, qb1, kv1, N1,
        hb2, WcatB + (size_t)1 * 12288, BcatB + (size_t)1 * 192, qb2, kv2, N2, nt1);

    gather64_kernel<<<gblocks, BLK, 0, stream>>>(
        cnt12, csr12, qb2, kv1, g2, N2,
        cnt21, csr21, qb1, kv2, g1, N1);

    updkqv_mfma<<<nt1 + nt2, BLK, 0, stream>>>(
        g1, AwbB + (size_t)0 * 4096, ab + (size_t)0 * 64, skip + 0, hb1, out, N1,
        g2, AwbB + (size_t)1 * 4096, ab + (size_t)1 * 64, skip + 1, hb2,
        out + (size_t)N1 * 128, N2,
        WcatB + (size_t)2 * 12288, BcatB + (size_t)2 * 192, qb1, kv1,
        WcatB + (size_t)3 * 12288, BcatB + (size_t)3 * 192, qb2, kv2,
        nt1, 0);

    // ---- layer 1 ----
    gather64_kernel<<<gblocks, BLK, 0, stream>>>(
        cnt12, csr12, qb2, kv1, g2, N2,
        cnt21, csr21, qb1, kv2, g1, N1);

    update2_mfma<<<nt1 + nt2, BLK, 0, stream>>>(
        g1, AwbB + (size_t)2 * 4096, ab + (size_t)2 * 64, skip + 2, hb1, out, N1,
        g2, AwbB + (size_t)3 * 4096, ab + (size_t)3 * 64, skip + 3, hb2,
        out + (size_t)N1 * 128, N2, nt1, 64);
}